// Round 1
// baseline (1619.223 us; speedup 1.0000x reference)
//
#include <hip/hip_runtime.h>
#include <hip/hip_bf16.h>

#define NPIX 4096          // 64*64
#define DIMC 512
#define ATT_SCALE 0.125f   // (512/8)^-0.5

// ---------------------------------------------------------------------------
// GEMM: Cout[b][o][p] = sum_c W[o][c] * Bin[b][c][p]  (+ optional residual)
// Tile 64(o) x 64(p), BK=16, 256 threads, 4x4 per thread.
// ---------------------------------------------------------------------------
__global__ __launch_bounds__(256) void gemm1x1(
    const float* __restrict__ W, const float* __restrict__ Bin,
    float* __restrict__ Cout, const float* __restrict__ Res,
    int Cd, long inBStride, long outBStride)
{
  const int b = blockIdx.z;
  const float* Bb = Bin + (long)b * inBStride;
  const int o0 = blockIdx.y * 64, p0 = blockIdx.x * 64;
  const int tid = threadIdx.x;
  const int tx = tid & 15, ty = tid >> 4;

  __shared__ float Ws[16][65];   // [kc][o], padded
  __shared__ float Bs[16][64];   // [kc][p]

  float acc[4][4] = {{0.f}};

  for (int c0 = 0; c0 < Cd; c0 += 16) {
    {
      const int o = tid >> 2, kc = (tid & 3) * 4;
      const float4 w4 = *(const float4*)&W[(long)(o0 + o) * Cd + c0 + kc];
      Ws[kc + 0][o] = w4.x; Ws[kc + 1][o] = w4.y;
      Ws[kc + 2][o] = w4.z; Ws[kc + 3][o] = w4.w;
    }
    {
      const int r = tid >> 4, p = (tid & 15) * 4;
      *(float4*)&Bs[r][p] = *(const float4*)&Bb[(long)(c0 + r) * NPIX + p0 + p];
    }
    __syncthreads();
    #pragma unroll
    for (int kc = 0; kc < 16; ++kc) {
      float a[4], bb[4];
      #pragma unroll
      for (int i = 0; i < 4; ++i) a[i] = Ws[kc][ty * 4 + i];
      #pragma unroll
      for (int j = 0; j < 4; ++j) bb[j] = Bs[kc][tx * 4 + j];
      #pragma unroll
      for (int i = 0; i < 4; ++i)
        #pragma unroll
        for (int j = 0; j < 4; ++j) acc[i][j] = fmaf(a[i], bb[j], acc[i][j]);
    }
    __syncthreads();
  }

  #pragma unroll
  for (int i = 0; i < 4; ++i) {
    const long row = (long)b * outBStride + (long)(o0 + ty * 4 + i) * NPIX + p0 + tx * 4;
    float4 v; v.x = acc[i][0]; v.y = acc[i][1]; v.z = acc[i][2]; v.w = acc[i][3];
    if (Res) {
      const float4 r4 = *(const float4*)&Res[row];
      v.x += r4.x; v.y += r4.y; v.z += r4.z; v.w += r4.w;
    }
    *(float4*)&Cout[row] = v;
  }
}

// ---------------------------------------------------------------------------
// Horizontal window attention. Window (b, iy): pixels (x, 4*iy + y2), seq = x*4+y2.
// q channels 0..255, k at +512, v at +1024 in qkv buffer. lepe = raw v row.
// grid (8 heads, 128 windows), 256 threads (one per seq position).
// ---------------------------------------------------------------------------
__global__ __launch_bounds__(256) void attn_h(
    const float* __restrict__ qkv, float* __restrict__ att)
{
  const int hh = blockIdx.x, wi = blockIdx.y;
  const int b = wi >> 4, iy = wi & 15;
  const int tid = threadIdx.x;
  const int pix = (tid >> 2) * 64 + iy * 4 + (tid & 3);
  const long base = (long)b * (3 * DIMC) * NPIX;
  const int ch = hh * 32;

  __shared__ __align__(16) float k_s[32 * 256];
  __shared__ __align__(16) float v_s[32 * 256];

  const float* Kg = qkv + base + (long)(DIMC + ch) * NPIX;
  const float* Vg = qkv + base + (long)(2 * DIMC + ch) * NPIX;
  for (int l = tid; l < 32 * 256; l += 256) {
    const int dd = l >> 8, j = l & 255;
    const int pj = (j >> 2) * 64 + iy * 4 + (j & 3);
    k_s[l] = Kg[(long)dd * NPIX + pj];
    v_s[l] = Vg[(long)dd * NPIX + pj];
  }
  const float* Qg = qkv + base + (long)ch * NPIX;
  float q[32];
  #pragma unroll
  for (int dd = 0; dd < 32; ++dd) q[dd] = Qg[(long)dd * NPIX + pix] * ATT_SCALE;
  __syncthreads();

  float m = -1e30f, lsum = 0.f, o[32];
  #pragma unroll
  for (int dd = 0; dd < 32; ++dd) o[dd] = 0.f;

  for (int jb = 0; jb < 256; jb += 4) {
    float s0 = 0.f, s1 = 0.f, s2 = 0.f, s3 = 0.f;
    #pragma unroll
    for (int dd = 0; dd < 32; ++dd) {
      const float4 k4 = *(const float4*)&k_s[dd * 256 + jb];
      s0 = fmaf(q[dd], k4.x, s0); s1 = fmaf(q[dd], k4.y, s1);
      s2 = fmaf(q[dd], k4.z, s2); s3 = fmaf(q[dd], k4.w, s3);
    }
    const float mn = fmaxf(fmaxf(fmaxf(s0, s1), fmaxf(s2, s3)), m);
    const float corr = __expf(m - mn);
    const float p0 = __expf(s0 - mn), p1 = __expf(s1 - mn);
    const float p2 = __expf(s2 - mn), p3 = __expf(s3 - mn);
    lsum = fmaf(lsum, corr, p0 + p1 + p2 + p3);
    #pragma unroll
    for (int dd = 0; dd < 32; ++dd) {
      const float4 v4 = *(const float4*)&v_s[dd * 256 + jb];
      o[dd] = fmaf(o[dd], corr, fmaf(p0, v4.x, fmaf(p1, v4.y, fmaf(p2, v4.z, p3 * v4.w))));
    }
    m = mn;
  }
  const float inv = 1.f / lsum;
  float* Og = att + (long)b * DIMC * NPIX + (long)ch * NPIX;
  #pragma unroll
  for (int dd = 0; dd < 32; ++dd)
    Og[(long)dd * NPIX + pix] = fmaf(o[dd], inv, v_s[dd * 256 + tid]);
}

// ---------------------------------------------------------------------------
// Vertical window attention + fused LePE (w_v_vert @ v_half).
// Window (b, ix): pixels (4*ix + x2, y), seq = x2*64 + y. Channels 256..511.
// ---------------------------------------------------------------------------
__global__ __launch_bounds__(256) void attn_v(
    const float* __restrict__ qkv, const float* __restrict__ Wv,
    float* __restrict__ att)
{
  const int hh = blockIdx.x, wi = blockIdx.y;
  const int b = wi >> 4, ix = wi & 15;
  const int tid = threadIdx.x;
  const int pix = (ix * 4 + (tid >> 6)) * 64 + (tid & 63);
  const long base = (long)b * (3 * DIMC) * NPIX;
  const int ch = 256 + hh * 32;

  __shared__ __align__(16) float a_s[32 * 256];   // first W_vert tile, then K
  __shared__ __align__(16) float v_s[32 * 256];

  const float* Vg = qkv + base + (long)(2 * DIMC + ch) * NPIX;
  for (int l = tid; l < 32 * 256; l += 256) {
    const int dd = l >> 8, j = l & 255;
    a_s[l] = Wv[(long)(hh * 32 + dd) * 256 + j];
    const int pj = (ix * 4 + (j >> 6)) * 64 + (j & 63);
    v_s[l] = Vg[(long)dd * NPIX + pj];
  }
  const float* Qg = qkv + base + (long)ch * NPIX;
  float q[32];
  #pragma unroll
  for (int dd = 0; dd < 32; ++dd) q[dd] = Qg[(long)dd * NPIX + pix] * ATT_SCALE;
  __syncthreads();

  // LePE: lepe[dd] = sum_c Wv[hh*32+dd][c] * v[b][256+c][pix]
  float lepe[32];
  #pragma unroll
  for (int dd = 0; dd < 32; ++dd) lepe[dd] = 0.f;
  const float* Vh = qkv + base + (long)(2 * DIMC + 256) * NPIX;
  for (int c = 0; c < 256; ++c) {
    const float vc = Vh[(long)c * NPIX + pix];
    #pragma unroll
    for (int dd = 0; dd < 32; ++dd) lepe[dd] = fmaf(a_s[dd * 256 + c], vc, lepe[dd]);
  }
  __syncthreads();
  const float* Kg = qkv + base + (long)(DIMC + ch) * NPIX;
  for (int l = tid; l < 32 * 256; l += 256) {
    const int dd = l >> 8, j = l & 255;
    const int pj = (ix * 4 + (j >> 6)) * 64 + (j & 63);
    a_s[l] = Kg[(long)dd * NPIX + pj];
  }
  __syncthreads();

  float m = -1e30f, lsum = 0.f, o[32];
  #pragma unroll
  for (int dd = 0; dd < 32; ++dd) o[dd] = 0.f;

  for (int jb = 0; jb < 256; jb += 4) {
    float s0 = 0.f, s1 = 0.f, s2 = 0.f, s3 = 0.f;
    #pragma unroll
    for (int dd = 0; dd < 32; ++dd) {
      const float4 k4 = *(const float4*)&a_s[dd * 256 + jb];
      s0 = fmaf(q[dd], k4.x, s0); s1 = fmaf(q[dd], k4.y, s1);
      s2 = fmaf(q[dd], k4.z, s2); s3 = fmaf(q[dd], k4.w, s3);
    }
    const float mn = fmaxf(fmaxf(fmaxf(s0, s1), fmaxf(s2, s3)), m);
    const float corr = __expf(m - mn);
    const float p0 = __expf(s0 - mn), p1 = __expf(s1 - mn);
    const float p2 = __expf(s2 - mn), p3 = __expf(s3 - mn);
    lsum = fmaf(lsum, corr, p0 + p1 + p2 + p3);
    #pragma unroll
    for (int dd = 0; dd < 32; ++dd) {
      const float4 v4 = *(const float4*)&v_s[dd * 256 + jb];
      o[dd] = fmaf(o[dd], corr, fmaf(p0, v4.x, fmaf(p1, v4.y, fmaf(p2, v4.z, p3 * v4.w))));
    }
    m = mn;
  }
  const float inv = 1.f / lsum;
  float* Og = att + (long)b * DIMC * NPIX + (long)(256 + hh * 32) * NPIX;
  #pragma unroll
  for (int dd = 0; dd < 32; ++dd)
    Og[(long)dd * NPIX + pix] = fmaf(o[dd], inv, lepe[dd]);
}

// ---------------------------------------------------------------------------
extern "C" void kernel_launch(void* const* d_in, const int* in_sizes, int n_in,
                              void* d_out, int out_size, void* d_ws, size_t ws_size,
                              hipStream_t stream) {
  const float* fmap      = (const float*)d_in[0];  // [8][512][64][64]
  const float* w_qk      = (const float*)d_in[1];  // [1024][512]
  const float* w_v       = (const float*)d_in[2];  // [512][512]
  const float* w_v_vert  = (const float*)d_in[3];  // [256][256]
  // d_in[4] = w_v_horiz: discarded by the reference (source bug)
  const float* w_proj    = (const float*)d_in[5];  // [512][512]
  float* out = (float*)d_out;

  // Workspace layout (f32):
  //   qkv: [8][1536][4096]  (q: ch 0..511, k: 512..1023, v: 1024..1535)  201.3 MB
  //   att: [8][512][4096]   (horiz out ch 0..255, vert out ch 256..511)   67.1 MB
  float* qkv = (float*)d_ws;
  float* att = qkv + (size_t)8 * 1536 * NPIX;

  const long fmapBS = (long)DIMC * NPIX;
  const long qkvBS  = (long)3 * DIMC * NPIX;

  dim3 blk(256);
  // QK projection -> qkv channels [0,1024)
  gemm1x1<<<dim3(64, 16, 8), blk, 0, stream>>>(w_qk, fmap, qkv, nullptr, DIMC, fmapBS, qkvBS);
  // V projection -> qkv channels [1024,1536)
  gemm1x1<<<dim3(64, 8, 8), blk, 0, stream>>>(w_v, fmap, qkv + (size_t)1024 * NPIX, nullptr, DIMC, fmapBS, qkvBS);
  // Window attention
  attn_h<<<dim3(8, 128), blk, 0, stream>>>(qkv, att);
  attn_v<<<dim3(8, 128), blk, 0, stream>>>(qkv, w_v_vert, att);
  // Final projection + residual
  gemm1x1<<<dim3(64, 8, 8), blk, 0, stream>>>(w_proj, att, out, fmap, DIMC, fmapBS, fmapBS);
}

// Round 2
// 735.374 us; speedup vs baseline: 2.2019x; 2.2019x over previous
//
#include <hip/hip_runtime.h>
#include <hip/hip_bf16.h>

#define NPIX 4096
#define ATT_SCALE 0.125f

typedef unsigned short ushort_t;
typedef __attribute__((ext_vector_type(8))) short bf16x8;
typedef __attribute__((ext_vector_type(4))) float f32x4;
typedef __attribute__((ext_vector_type(8))) unsigned short us8;

__device__ __forceinline__ float bf2f(ushort_t u) {
  union { unsigned int i; float f; } v; v.i = ((unsigned int)u) << 16; return v.f;
}
__device__ __forceinline__ ushort_t f2bf(float f) {
  union { float f; unsigned int i; } v; v.f = f;
  unsigned int r = v.i + 0x7fffu + ((v.i >> 16) & 1u);
  return (ushort_t)(r >> 16);
}

__device__ __forceinline__ void gload16(const void* g, void* l) {
  __builtin_amdgcn_global_load_lds(
      (const __attribute__((address_space(1))) void*)g,
      (__attribute__((address_space(3))) void*)l, 16, 0, 0);
}

// ---------------------------------------------------------------------------
// f32 -> bf16 cast (n multiple of 4)
// ---------------------------------------------------------------------------
__global__ __launch_bounds__(256) void cast_bf16(const float* __restrict__ s,
                                                 ushort_t* __restrict__ d, int n) {
  int i = (blockIdx.x * 256 + threadIdx.x) * 4;
  if (i < n) {
    float4 v = *(const float4*)&s[i];
    ushort4 o = make_ushort4(f2bf(v.x), f2bf(v.y), f2bf(v.z), f2bf(v.w));
    *(ushort4*)&d[i] = o;
  }
}

// ---------------------------------------------------------------------------
// W_lepe[i][j] = sum_c w_v_vert[i][c] * w_v[256+c][j]   (256x512, bf16 out)
// grid 256 blocks x 256 threads
// ---------------------------------------------------------------------------
__global__ __launch_bounds__(256) void lepe_w(const float* __restrict__ wvv,
                                              const float* __restrict__ wv,
                                              ushort_t* __restrict__ out) {
  const int i = blockIdx.x, tid = threadIdx.x;
  float a0 = 0.f, a1 = 0.f;
  for (int c = 0; c < 256; ++c) {
    const float wc = wvv[i * 256 + c];
    a0 = fmaf(wc, wv[(size_t)(256 + c) * 512 + tid], a0);
    a1 = fmaf(wc, wv[(size_t)(256 + c) * 512 + 256 + tid], a1);
  }
  out[(size_t)i * 512 + tid] = f2bf(a0);
  out[(size_t)i * 512 + 256 + tid] = f2bf(a1);
}

// ---------------------------------------------------------------------------
// fmap [b][512][4096] f32  ->  XT [b][4096][512] bf16  (64x64 tiles)
// ---------------------------------------------------------------------------
__global__ __launch_bounds__(256) void transpose_cast(const float* __restrict__ fmap,
                                                      ushort_t* __restrict__ XT) {
  const int b = blockIdx.z, p0 = blockIdx.x * 64, c0 = blockIdx.y * 64;
  const int tid = threadIdx.x;
  __shared__ float t[64][65];
  const float* src = fmap + ((size_t)b * 512 + c0) * NPIX + p0;
  const int pr = tid & 63;
  #pragma unroll
  for (int i = 0; i < 16; ++i) {
    const int cr = i * 4 + (tid >> 6);
    t[cr][pr] = src[(size_t)cr * NPIX + pr];
  }
  __syncthreads();
  const int pw = tid >> 2, cwb = (tid & 3) * 16;
  us8 o0, o1;
  #pragma unroll
  for (int i = 0; i < 8; ++i) o0[i] = f2bf(t[cwb + i][pw]);
  #pragma unroll
  for (int i = 0; i < 8; ++i) o1[i] = f2bf(t[cwb + 8 + i][pw]);
  ushort_t* dst = XT + ((size_t)b * NPIX + p0 + pw) * 512 + c0 + cwb;
  *(us8*)&dst[0] = o0;
  *(us8*)&dst[8] = o1;
}

// ---------------------------------------------------------------------------
// MFMA GEMM: C[b][o][p] = A[o][:] . B[b][p][:]   (K=512, N=4096)
// A: bf16 [M][512], B: bf16 [4096][512] (both K-contiguous).
// 128x128 tile, BK=32, 4 waves (2x2 of 64x64), mfma_f32_16x16x32_bf16.
// LDS XOR-swizzle: chunk' = chunk ^ ((row>>1)&3)  (16B chunks, 64B rows).
// mode 0: store bf16 to C. mode 1: store f32 + residual.
// ---------------------------------------------------------------------------
__global__ __launch_bounds__(256) void gemm_mfma(
    const ushort_t* __restrict__ A, const ushort_t* __restrict__ B,
    void* __restrict__ Cout, const float* __restrict__ Res,
    long bStrideB, long bStrideC, int mode)
{
  const int b = blockIdx.z;
  const int p0 = blockIdx.x * 128;   // N
  const int o0 = blockIdx.y * 128;   // M
  const int tid = threadIdx.x;
  const int lane = tid & 63, w = tid >> 6;
  const int wrow = (w >> 1) * 64, wcol = (w & 1) * 64;

  __shared__ __attribute__((aligned(16))) short As[128 * 32];
  __shared__ __attribute__((aligned(16))) short Bs[128 * 32];

  const ushort_t* Bb = B + (size_t)b * bStrideB;

  f32x4 acc[4][4];
  #pragma unroll
  for (int m = 0; m < 4; ++m)
    #pragma unroll
    for (int n = 0; n < 4; ++n) acc[m][n] = (f32x4){0.f, 0.f, 0.f, 0.f};

  const int cl = lane & 3;

  for (int kt = 0; kt < 16; ++kt) {
    const int kb = kt * 32;
    #pragma unroll
    for (int i = 0; i < 2; ++i) {
      const int r = w * 32 + i * 16 + (lane >> 2);
      const int cs = cl ^ ((r >> 1) & 3);
      gload16(&A[(size_t)(o0 + r) * 512 + kb + cs * 8], &As[(w * 32 + i * 16) * 32]);
      gload16(&Bb[(size_t)(p0 + r) * 512 + kb + cs * 8], &Bs[(w * 32 + i * 16) * 32]);
    }
    __syncthreads();
    bf16x8 af[4], bfr[4];
    #pragma unroll
    for (int m = 0; m < 4; ++m) {
      const int row = wrow + m * 16 + (lane & 15);
      const int c = (lane >> 4) ^ ((row >> 1) & 3);
      af[m] = *(const bf16x8*)&As[row * 32 + c * 8];
    }
    #pragma unroll
    for (int n = 0; n < 4; ++n) {
      const int row = wcol + n * 16 + (lane & 15);
      const int c = (lane >> 4) ^ ((row >> 1) & 3);
      bfr[n] = *(const bf16x8*)&Bs[row * 32 + c * 8];
    }
    #pragma unroll
    for (int m = 0; m < 4; ++m)
      #pragma unroll
      for (int n = 0; n < 4; ++n)
        acc[m][n] = __builtin_amdgcn_mfma_f32_16x16x32_bf16(af[m], bfr[n], acc[m][n], 0, 0, 0);
    __syncthreads();
  }

  const int fr = lane & 15, fq = lane >> 4;
  if (mode == 0) {
    ushort_t* C = (ushort_t*)Cout + (size_t)b * bStrideC;
    #pragma unroll
    for (int m = 0; m < 4; ++m)
      #pragma unroll
      for (int n = 0; n < 4; ++n) {
        const int col = p0 + wcol + n * 16 + fr;
        #pragma unroll
        for (int j = 0; j < 4; ++j) {
          const int row = o0 + wrow + m * 16 + fq * 4 + j;
          C[(size_t)row * NPIX + col] = f2bf(acc[m][n][j]);
        }
      }
  } else {
    float* C = (float*)Cout + (size_t)b * bStrideC;
    const float* R = Res + (size_t)b * bStrideC;
    #pragma unroll
    for (int m = 0; m < 4; ++m)
      #pragma unroll
      for (int n = 0; n < 4; ++n) {
        const int col = p0 + wcol + n * 16 + fr;
        #pragma unroll
        for (int j = 0; j < 4; ++j) {
          const int row = o0 + wrow + m * 16 + fq * 4 + j;
          const size_t idx = (size_t)row * NPIX + col;
          C[idx] = acc[m][n][j] + R[idx];
        }
      }
  }
}

// ---------------------------------------------------------------------------
// Horizontal window attention. qkv bf16 [b][1792][4096]:
//   q rows 0..511, k 512..1023, v 1024..1535, lepe 1536..1791.
// Window (b,iy): pix = x*64 + iy*4 + y2, seq = x*4+y2. lepe_h = raw v.
// Writes attT bf16 [b][4096][512] channels hh*32..+32.
// ---------------------------------------------------------------------------
__global__ __launch_bounds__(256) void attn_h(const ushort_t* __restrict__ qkv,
                                              ushort_t* __restrict__ attT) {
  const int hh = blockIdx.x, wi = blockIdx.y;
  const int b = wi >> 4, iy = wi & 15;
  const int tid = threadIdx.x;
  const int pix = (tid >> 2) * 64 + iy * 4 + (tid & 3);
  const size_t base = (size_t)b * 1792 * NPIX;
  const int ch = hh * 32;

  __shared__ __align__(16) float k_s[32 * 256];
  __shared__ __align__(16) float v_s[32 * 256];

  const ushort_t* Kg = qkv + base + (size_t)(512 + ch) * NPIX;
  const ushort_t* Vg = qkv + base + (size_t)(1024 + ch) * NPIX;
  for (int l = tid; l < 2048; l += 256) {
    const int dd = l >> 6, j4 = (l & 63) * 4;
    const int pjb = (j4 >> 2) * 64 + iy * 4;
    const ushort4 k4 = *(const ushort4*)&Kg[(size_t)dd * NPIX + pjb];
    const ushort4 v4 = *(const ushort4*)&Vg[(size_t)dd * NPIX + pjb];
    float4 kf = make_float4(bf2f(k4.x), bf2f(k4.y), bf2f(k4.z), bf2f(k4.w));
    float4 vf = make_float4(bf2f(v4.x), bf2f(v4.y), bf2f(v4.z), bf2f(v4.w));
    *(float4*)&k_s[dd * 256 + j4] = kf;
    *(float4*)&v_s[dd * 256 + j4] = vf;
  }
  const ushort_t* Qg = qkv + base + (size_t)ch * NPIX;
  float q[32];
  #pragma unroll
  for (int dd = 0; dd < 32; ++dd) q[dd] = bf2f(Qg[(size_t)dd * NPIX + pix]) * ATT_SCALE;
  __syncthreads();

  float m = -1e30f, lsum = 0.f, o[32];
  #pragma unroll
  for (int dd = 0; dd < 32; ++dd) o[dd] = 0.f;

  for (int jb = 0; jb < 256; jb += 4) {
    float s0 = 0.f, s1 = 0.f, s2 = 0.f, s3 = 0.f;
    #pragma unroll
    for (int dd = 0; dd < 32; ++dd) {
      const float4 k4 = *(const float4*)&k_s[dd * 256 + jb];
      s0 = fmaf(q[dd], k4.x, s0); s1 = fmaf(q[dd], k4.y, s1);
      s2 = fmaf(q[dd], k4.z, s2); s3 = fmaf(q[dd], k4.w, s3);
    }
    const float mn = fmaxf(fmaxf(fmaxf(s0, s1), fmaxf(s2, s3)), m);
    const float corr = __expf(m - mn);
    const float p0 = __expf(s0 - mn), p1 = __expf(s1 - mn);
    const float p2 = __expf(s2 - mn), p3 = __expf(s3 - mn);
    lsum = fmaf(lsum, corr, p0 + p1 + p2 + p3);
    #pragma unroll
    for (int dd = 0; dd < 32; ++dd) {
      const float4 v4 = *(const float4*)&v_s[dd * 256 + jb];
      o[dd] = fmaf(o[dd], corr, fmaf(p0, v4.x, fmaf(p1, v4.y, fmaf(p2, v4.z, p3 * v4.w))));
    }
    m = mn;
  }
  const float inv = 1.f / lsum;
  ushort_t* Og = attT + ((size_t)b * NPIX + pix) * 512 + ch;
  #pragma unroll
  for (int g = 0; g < 4; ++g) {
    us8 pack;
    #pragma unroll
    for (int t = 0; t < 8; ++t) {
      const int dd = g * 8 + t;
      pack[t] = f2bf(fmaf(o[dd], inv, v_s[dd * 256 + tid]));
    }
    *(us8*)&Og[g * 8] = pack;
  }
}

// ---------------------------------------------------------------------------
// Vertical window attention. Window (b,ix): pix = (ix*4+x2)*64 + y, seq = x2*64+y.
// Channels 256..511; lepe from qkv rows 1536+hh*32.
// ---------------------------------------------------------------------------
__global__ __launch_bounds__(256) void attn_v(const ushort_t* __restrict__ qkv,
                                              ushort_t* __restrict__ attT) {
  const int hh = blockIdx.x, wi = blockIdx.y;
  const int b = wi >> 4, ix = wi & 15;
  const int tid = threadIdx.x;
  const int pix = (ix * 4 + (tid >> 6)) * 64 + (tid & 63);
  const size_t base = (size_t)b * 1792 * NPIX;
  const int ch = 256 + hh * 32;

  __shared__ __align__(16) float k_s[32 * 256];
  __shared__ __align__(16) float v_s[32 * 256];

  const ushort_t* Kg = qkv + base + (size_t)(512 + ch) * NPIX;
  const ushort_t* Vg = qkv + base + (size_t)(1024 + ch) * NPIX;
  for (int l = tid; l < 2048; l += 256) {
    const int dd = l >> 6, j4 = (l & 63) * 4;
    const int pjb = (ix * 4 + (j4 >> 6)) * 64 + (j4 & 63);
    const ushort4 k4 = *(const ushort4*)&Kg[(size_t)dd * NPIX + pjb];
    const ushort4 v4 = *(const ushort4*)&Vg[(size_t)dd * NPIX + pjb];
    float4 kf = make_float4(bf2f(k4.x), bf2f(k4.y), bf2f(k4.z), bf2f(k4.w));
    float4 vf = make_float4(bf2f(v4.x), bf2f(v4.y), bf2f(v4.z), bf2f(v4.w));
    *(float4*)&k_s[dd * 256 + j4] = kf;
    *(float4*)&v_s[dd * 256 + j4] = vf;
  }
  const ushort_t* Qg = qkv + base + (size_t)ch * NPIX;
  const ushort_t* Lg = qkv + base + (size_t)(1536 + hh * 32) * NPIX;
  float q[32], lepe[32];
  #pragma unroll
  for (int dd = 0; dd < 32; ++dd) {
    q[dd] = bf2f(Qg[(size_t)dd * NPIX + pix]) * ATT_SCALE;
    lepe[dd] = bf2f(Lg[(size_t)dd * NPIX + pix]);
  }
  __syncthreads();

  float m = -1e30f, lsum = 0.f, o[32];
  #pragma unroll
  for (int dd = 0; dd < 32; ++dd) o[dd] = 0.f;

  for (int jb = 0; jb < 256; jb += 4) {
    float s0 = 0.f, s1 = 0.f, s2 = 0.f, s3 = 0.f;
    #pragma unroll
    for (int dd = 0; dd < 32; ++dd) {
      const float4 k4 = *(const float4*)&k_s[dd * 256 + jb];
      s0 = fmaf(q[dd], k4.x, s0); s1 = fmaf(q[dd], k4.y, s1);
      s2 = fmaf(q[dd], k4.z, s2); s3 = fmaf(q[dd], k4.w, s3);
    }
    const float mn = fmaxf(fmaxf(fmaxf(s0, s1), fmaxf(s2, s3)), m);
    const float corr = __expf(m - mn);
    const float p0 = __expf(s0 - mn), p1 = __expf(s1 - mn);
    const float p2 = __expf(s2 - mn), p3 = __expf(s3 - mn);
    lsum = fmaf(lsum, corr, p0 + p1 + p2 + p3);
    #pragma unroll
    for (int dd = 0; dd < 32; ++dd) {
      const float4 v4 = *(const float4*)&v_s[dd * 256 + jb];
      o[dd] = fmaf(o[dd], corr, fmaf(p0, v4.x, fmaf(p1, v4.y, fmaf(p2, v4.z, p3 * v4.w))));
    }
    m = mn;
  }
  const float inv = 1.f / lsum;
  ushort_t* Og = attT + ((size_t)b * NPIX + pix) * 512 + ch;
  #pragma unroll
  for (int g = 0; g < 4; ++g) {
    us8 pack;
    #pragma unroll
    for (int t = 0; t < 8; ++t) {
      const int dd = g * 8 + t;
      pack[t] = f2bf(fmaf(o[dd], inv, lepe[dd]));
    }
    *(us8*)&Og[g * 8] = pack;
  }
}

// ---------------------------------------------------------------------------
extern "C" void kernel_launch(void* const* d_in, const int* in_sizes, int n_in,
                              void* d_out, int out_size, void* d_ws, size_t ws_size,
                              hipStream_t stream) {
  const float* fmap     = (const float*)d_in[0];
  const float* w_qk     = (const float*)d_in[1];
  const float* w_v      = (const float*)d_in[2];
  const float* w_v_vert = (const float*)d_in[3];
  const float* w_proj   = (const float*)d_in[5];
  float* out = (float*)d_out;

  // ws layout (bf16 elements):
  ushort_t* XT   = (ushort_t*)d_ws;                       // [8][4096][512]
  ushort_t* qkvb = XT + (size_t)8 * NPIX * 512;           // [8][1792][4096]
  ushort_t* attT = qkvb + (size_t)8 * 1792 * NPIX;        // [8][4096][512]
  ushort_t* WA   = attT + (size_t)8 * NPIX * 512;         // [1792][512]
  ushort_t* WPb  = WA + (size_t)1792 * 512;               // [512][512]

  dim3 blk(256);
  // weight casts: w_qk -> WA[0:1024], w_v -> WA[1024:1536], w_proj -> WPb
  cast_bf16<<<512, blk, 0, stream>>>(w_qk, WA, 1024 * 512);
  cast_bf16<<<256, blk, 0, stream>>>(w_v, WA + (size_t)1024 * 512, 512 * 512);
  cast_bf16<<<256, blk, 0, stream>>>(w_proj, WPb, 512 * 512);
  // W_lepe -> WA[1536:1792]
  lepe_w<<<256, blk, 0, stream>>>(w_v_vert, w_v, WA + (size_t)1536 * 512);
  // fmap -> XT (transpose + cast)
  transpose_cast<<<dim3(64, 8, 8), blk, 0, stream>>>(fmap, XT);
  // fused QKV+LePE GEMM: qkvb[b][1792][4096] bf16
  gemm_mfma<<<dim3(32, 14, 8), blk, 0, stream>>>(
      WA, XT, qkvb, nullptr, (long)NPIX * 512, (long)1792 * NPIX, 0);
  // window attention -> attT bf16 [b][4096][512]
  attn_h<<<dim3(8, 128), blk, 0, stream>>>(qkvb, attT);
  attn_v<<<dim3(8, 128), blk, 0, stream>>>(qkvb, attT);
  // proj + residual -> out f32
  gemm_mfma<<<dim3(32, 4, 8), blk, 0, stream>>>(
      WPb, attT, out, fmap, (long)NPIX * 512, (long)512 * NPIX, 1);
}

// Round 4
// 273.483 us; speedup vs baseline: 5.9208x; 2.6889x over previous
//
#include <hip/hip_runtime.h>
#include <hip/hip_bf16.h>

#define NPIX 4096
#define ATT_SCALE 0.125f

typedef unsigned short ushort_t;
typedef __attribute__((ext_vector_type(8))) short bf16x8;
typedef __attribute__((ext_vector_type(4))) float f32x4;
typedef __attribute__((ext_vector_type(8))) unsigned short us8;

__device__ __forceinline__ float bf2f(ushort_t u) {
  union { unsigned int i; float f; } v; v.i = ((unsigned int)u) << 16; return v.f;
}
__device__ __forceinline__ ushort_t f2bf(float f) {
  union { float f; unsigned int i; } v; v.f = f;
  unsigned int r = v.i + 0x7fffu + ((v.i >> 16) & 1u);
  return (ushort_t)(r >> 16);
}

__device__ __forceinline__ void gload16(const void* g, void* l) {
  __builtin_amdgcn_global_load_lds(
      (const __attribute__((address_space(1))) void*)g,
      (__attribute__((address_space(3))) void*)l, 16, 0, 0);
}

// ---------------------------------------------------------------------------
// f32 -> bf16 cast (n multiple of 4)
// ---------------------------------------------------------------------------
__global__ __launch_bounds__(256) void cast_bf16(const float* __restrict__ s,
                                                 ushort_t* __restrict__ d, int n) {
  int i = (blockIdx.x * 256 + threadIdx.x) * 4;
  if (i < n) {
    float4 v = *(const float4*)&s[i];
    ushort4 o = make_ushort4(f2bf(v.x), f2bf(v.y), f2bf(v.z), f2bf(v.w));
    *(ushort4*)&d[i] = o;
  }
}

// ---------------------------------------------------------------------------
// W_lepe[i][j] = sum_c w_v_vert[i][c] * w_v[256+c][j]   (256x512, bf16 out)
// ---------------------------------------------------------------------------
__global__ __launch_bounds__(256) void lepe_w(const float* __restrict__ wvv,
                                              const float* __restrict__ wv,
                                              ushort_t* __restrict__ out) {
  const int i = blockIdx.x, tid = threadIdx.x;
  float a0 = 0.f, a1 = 0.f;
  for (int c = 0; c < 256; ++c) {
    const float wc = wvv[i * 256 + c];
    a0 = fmaf(wc, wv[(size_t)(256 + c) * 512 + tid], a0);
    a1 = fmaf(wc, wv[(size_t)(256 + c) * 512 + 256 + tid], a1);
  }
  out[(size_t)i * 512 + tid] = f2bf(a0);
  out[(size_t)i * 512 + 256 + tid] = f2bf(a1);
}

// ---------------------------------------------------------------------------
// fmap [b][512][4096] f32  ->  XT [b][4096][512] bf16
// ---------------------------------------------------------------------------
__global__ __launch_bounds__(256) void transpose_cast(const float* __restrict__ fmap,
                                                      ushort_t* __restrict__ XT) {
  const int b = blockIdx.z, p0 = blockIdx.x * 64, c0 = blockIdx.y * 64;
  const int tid = threadIdx.x;
  __shared__ float t[64][65];
  const float* src = fmap + ((size_t)b * 512 + c0) * NPIX + p0;
  const int pr = tid & 63;
  #pragma unroll
  for (int i = 0; i < 16; ++i) {
    const int cr = i * 4 + (tid >> 6);
    t[cr][pr] = src[(size_t)cr * NPIX + pr];
  }
  __syncthreads();
  const int pw = tid >> 2, cwb = (tid & 3) * 16;
  us8 o0, o1;
  #pragma unroll
  for (int i = 0; i < 8; ++i) o0[i] = f2bf(t[cwb + i][pw]);
  #pragma unroll
  for (int i = 0; i < 8; ++i) o1[i] = f2bf(t[cwb + 8 + i][pw]);
  ushort_t* dst = XT + ((size_t)b * NPIX + p0 + pw) * 512 + c0 + cwb;
  *(us8*)&dst[0] = o0;
  *(us8*)&dst[8] = o1;
}

// ---------------------------------------------------------------------------
// MFMA GEMM: C[b][o][p] = A[o][:] . B[b][p][:]   (K=512, N=4096)
// ---------------------------------------------------------------------------
__global__ __launch_bounds__(256) void gemm_mfma(
    const ushort_t* __restrict__ A, const ushort_t* __restrict__ B,
    void* __restrict__ Cout, const float* __restrict__ Res,
    long bStrideB, long bStrideC, int mode)
{
  const int b = blockIdx.z;
  const int p0 = blockIdx.x * 128;
  const int o0 = blockIdx.y * 128;
  const int tid = threadIdx.x;
  const int lane = tid & 63, w = tid >> 6;
  const int wrow = (w >> 1) * 64, wcol = (w & 1) * 64;

  __shared__ __attribute__((aligned(16))) short As[128 * 32];
  __shared__ __attribute__((aligned(16))) short Bs[128 * 32];

  const ushort_t* Bb = B + (size_t)b * bStrideB;

  f32x4 acc[4][4];
  #pragma unroll
  for (int m = 0; m < 4; ++m)
    #pragma unroll
    for (int n = 0; n < 4; ++n) acc[m][n] = (f32x4){0.f, 0.f, 0.f, 0.f};

  const int cl = lane & 3;

  for (int kt = 0; kt < 16; ++kt) {
    const int kb = kt * 32;
    #pragma unroll
    for (int i = 0; i < 2; ++i) {
      const int r = w * 32 + i * 16 + (lane >> 2);
      const int cs = cl ^ ((r >> 1) & 3);
      gload16(&A[(size_t)(o0 + r) * 512 + kb + cs * 8], &As[(w * 32 + i * 16) * 32]);
      gload16(&Bb[(size_t)(p0 + r) * 512 + kb + cs * 8], &Bs[(w * 32 + i * 16) * 32]);
    }
    __syncthreads();
    bf16x8 af[4], bfr[4];
    #pragma unroll
    for (int m = 0; m < 4; ++m) {
      const int row = wrow + m * 16 + (lane & 15);
      const int c = (lane >> 4) ^ ((row >> 1) & 3);
      af[m] = *(const bf16x8*)&As[row * 32 + c * 8];
    }
    #pragma unroll
    for (int n = 0; n < 4; ++n) {
      const int row = wcol + n * 16 + (lane & 15);
      const int c = (lane >> 4) ^ ((row >> 1) & 3);
      bfr[n] = *(const bf16x8*)&Bs[row * 32 + c * 8];
    }
    #pragma unroll
    for (int m = 0; m < 4; ++m)
      #pragma unroll
      for (int n = 0; n < 4; ++n)
        acc[m][n] = __builtin_amdgcn_mfma_f32_16x16x32_bf16(af[m], bfr[n], acc[m][n], 0, 0, 0);
    __syncthreads();
  }

  const int fr = lane & 15, fq = lane >> 4;
  if (mode == 0) {
    ushort_t* C = (ushort_t*)Cout + (size_t)b * bStrideC;
    #pragma unroll
    for (int m = 0; m < 4; ++m)
      #pragma unroll
      for (int n = 0; n < 4; ++n) {
        const int col = p0 + wcol + n * 16 + fr;
        #pragma unroll
        for (int j = 0; j < 4; ++j) {
          const int row = o0 + wrow + m * 16 + fq * 4 + j;
          C[(size_t)row * NPIX + col] = f2bf(acc[m][n][j]);
        }
      }
  } else {
    float* C = (float*)Cout + (size_t)b * bStrideC;
    const float* R = Res + (size_t)b * bStrideC;
    #pragma unroll
    for (int m = 0; m < 4; ++m)
      #pragma unroll
      for (int n = 0; n < 4; ++n) {
        const int col = p0 + wcol + n * 16 + fr;
        #pragma unroll
        for (int j = 0; j < 4; ++j) {
          const int row = o0 + wrow + m * 16 + fq * 4 + j;
          const size_t idx = (size_t)row * NPIX + col;
          C[idx] = acc[m][n][j] + R[idx];
        }
      }
  }
}

// ---------------------------------------------------------------------------
// MFMA flash attention over one (head, window). blockIdx: (head 8, window 128,
// branch 2: 0=horizontal, 1=vertical). 4 waves; wave w owns q rows [w*64,w*64+64).
//
// Seq->pixel maps: H: pix = (j>>2)*64 + iw*4 + (j&3);  V: pix = iw*256 + j.
// Swapped QK^T: S^T = mfma(A=K_frag, B=Q_frag) so the q index is lane-local
// (col=lane&15) and row-softmax reduces with shfl_xor 16/32 only.
// P re-fragmented for PV via per-wave LDS tile. lepe_h = raw V (VT_lds),
// lepe_v = precomputed lepe rows (1536+hh*32) in qkv.
// ---------------------------------------------------------------------------
__global__ __launch_bounds__(256) void attn_mfma(const ushort_t* __restrict__ qkv,
                                                 ushort_t* __restrict__ attT) {
  const int hh = blockIdx.x, wi = blockIdx.y, vert = blockIdx.z;
  const int b = wi >> 4, iw = wi & 15;
  const int tid = threadIdx.x;
  const int lane = tid & 63, w = tid >> 6;
  const int g = lane >> 4, q16 = lane & 15;
  const int qbase = w * 64;
  const size_t base = (size_t)b * 1792 * NPIX;
  const int ch = vert * 256 + hh * 32;

  __shared__ __attribute__((aligned(16))) ushort_t K_lds[256 * 40];   // [j][d] pad40
  __shared__ __attribute__((aligned(16))) ushort_t VT_lds[32 * 264];  // [d][j] pad264
  __shared__ __attribute__((aligned(16))) ushort_t P_lds[4][64 * 40]; // per wave [q][jl]

  // ---- stage K (transposed to [j][d]) and V (as [d][j]) ----
  const ushort_t* Kg = qkv + base + (size_t)(512 + ch) * NPIX;
  const ushort_t* Vg = qkv + base + (size_t)(1024 + ch) * NPIX;
  #pragma unroll
  for (int it = 0; it < 8; ++it) {
    const int idx = it * 256 + tid;
    const int d = idx >> 6, jg = idx & 63;
    const int pb = vert ? iw * 256 + jg * 4 : jg * 64 + iw * 4;
    const ushort4 k4 = *(const ushort4*)&Kg[(size_t)d * NPIX + pb];
    const ushort4 v4 = *(const ushort4*)&Vg[(size_t)d * NPIX + pb];
    K_lds[(jg * 4 + 0) * 40 + d] = k4.x;
    K_lds[(jg * 4 + 1) * 40 + d] = k4.y;
    K_lds[(jg * 4 + 2) * 40 + d] = k4.z;
    K_lds[(jg * 4 + 3) * 40 + d] = k4.w;
    *(ushort4*)&VT_lds[d * 264 + jg * 4] = v4;
  }

  // ---- Q fragments (B operand): row q = qbase+qt*16+q16, k = d = g*8+s ----
  const ushort_t* Qg = qkv + base + (size_t)ch * NPIX;
  bf16x8 qf[4];
  #pragma unroll
  for (int qt = 0; qt < 4; ++qt) {
    const int q = qbase + qt * 16 + q16;
    const int qp = vert ? iw * 256 + q : (q >> 2) * 64 + iw * 4 + (q & 3);
    bf16x8 f;
    #pragma unroll
    for (int s = 0; s < 8; ++s)
      f[s] = (short)Qg[(size_t)(g * 8 + s) * NPIX + qp];
    qf[qt] = f;
  }
  __syncthreads();

  float m[4], l[4];
  f32x4 o[4][2];
  #pragma unroll
  for (int qt = 0; qt < 4; ++qt) {
    m[qt] = -1e30f; l[qt] = 0.f;
    o[qt][0] = (f32x4){0.f, 0.f, 0.f, 0.f};
    o[qt][1] = (f32x4){0.f, 0.f, 0.f, 0.f};
  }

  const f32x4 zero4 = (f32x4){0.f, 0.f, 0.f, 0.f};

  for (int jc = 0; jc < 8; ++jc) {           // 32 k-positions per chunk
    // S^T block: rows j (chunk-local 32), cols q (wave's 64)
    bf16x8 kf0 = *(const bf16x8*)&K_lds[(jc * 32 + q16) * 40 + g * 8];
    bf16x8 kf1 = *(const bf16x8*)&K_lds[(jc * 32 + 16 + q16) * 40 + g * 8];
    f32x4 st[2][4];
    #pragma unroll
    for (int qt = 0; qt < 4; ++qt) {
      st[0][qt] = __builtin_amdgcn_mfma_f32_16x16x32_bf16(kf0, qf[qt], zero4, 0, 0, 0);
      st[1][qt] = __builtin_amdgcn_mfma_f32_16x16x32_bf16(kf1, qf[qt], zero4, 0, 0, 0);
    }
    float corr[4];
    #pragma unroll
    for (int qt = 0; qt < 4; ++qt) {
      st[0][qt] *= ATT_SCALE;
      st[1][qt] *= ATT_SCALE;
      float pm = fmaxf(fmaxf(fmaxf(st[0][qt][0], st[0][qt][1]), fmaxf(st[0][qt][2], st[0][qt][3])),
                       fmaxf(fmaxf(st[1][qt][0], st[1][qt][1]), fmaxf(st[1][qt][2], st[1][qt][3])));
      pm = fmaxf(pm, __shfl_xor(pm, 16));
      pm = fmaxf(pm, __shfl_xor(pm, 32));
      const float mn = fmaxf(m[qt], pm);
      corr[qt] = __expf(m[qt] - mn);
      m[qt] = mn;
      float rs = 0.f;
      ushort4 pk0, pk1;
      {
        const float p0 = __expf(st[0][qt][0] - mn), p1 = __expf(st[0][qt][1] - mn);
        const float p2 = __expf(st[0][qt][2] - mn), p3 = __expf(st[0][qt][3] - mn);
        rs += p0 + p1 + p2 + p3;
        pk0 = make_ushort4(f2bf(p0), f2bf(p1), f2bf(p2), f2bf(p3));
      }
      {
        const float p0 = __expf(st[1][qt][0] - mn), p1 = __expf(st[1][qt][1] - mn);
        const float p2 = __expf(st[1][qt][2] - mn), p3 = __expf(st[1][qt][3] - mn);
        rs += p0 + p1 + p2 + p3;
        pk1 = make_ushort4(f2bf(p0), f2bf(p1), f2bf(p2), f2bf(p3));
      }
      rs += __shfl_xor(rs, 16);
      rs += __shfl_xor(rs, 32);
      l[qt] = l[qt] * corr[qt] + rs;
      *(ushort4*)&P_lds[w][(qt * 16 + q16) * 40 + g * 4]      = pk0;
      *(ushort4*)&P_lds[w][(qt * 16 + q16) * 40 + 16 + g * 4] = pk1;
    }
    // rescale O by corr (row q = qbase + qt*16 + g*4 + jj)
    #pragma unroll
    for (int qt = 0; qt < 4; ++qt) {
      float cr[4];
      #pragma unroll
      for (int jj = 0; jj < 4; ++jj) cr[jj] = __shfl(corr[qt], g * 4 + jj);
      #pragma unroll
      for (int dt = 0; dt < 2; ++dt)
        #pragma unroll
        for (int jj = 0; jj < 4; ++jj) o[qt][dt][jj] *= cr[jj];
    }
    // PV: O[q][d] += P[q][jl] V[jl][d]
    bf16x8 vf0 = *(const bf16x8*)&VT_lds[q16 * 264 + jc * 32 + g * 8];
    bf16x8 vf1 = *(const bf16x8*)&VT_lds[(16 + q16) * 264 + jc * 32 + g * 8];
    #pragma unroll
    for (int qt = 0; qt < 4; ++qt) {
      bf16x8 pf = *(const bf16x8*)&P_lds[w][(qt * 16 + q16) * 40 + g * 8];
      o[qt][0] = __builtin_amdgcn_mfma_f32_16x16x32_bf16(pf, vf0, o[qt][0], 0, 0, 0);
      o[qt][1] = __builtin_amdgcn_mfma_f32_16x16x32_bf16(pf, vf1, o[qt][1], 0, 0, 0);
    }
  }

  // ---- epilogue: normalize, add lepe, store to attT[b][pix][512] ----
  const ushort_t* Lg = qkv + base + (size_t)(1536 + hh * 32) * NPIX;
  #pragma unroll
  for (int qt = 0; qt < 4; ++qt) {
    const float linv = 1.f / l[qt];
    float li[4];
    #pragma unroll
    for (int jj = 0; jj < 4; ++jj) li[jj] = __shfl(linv, g * 4 + jj);
    #pragma unroll
    for (int dt = 0; dt < 2; ++dt) {
      const int d = dt * 16 + q16;
      #pragma unroll
      for (int jj = 0; jj < 4; ++jj) {
        const int q = qbase + qt * 16 + g * 4 + jj;
        float lep;
        if (vert) lep = bf2f(Lg[(size_t)d * NPIX + iw * 256 + q]);
        else      lep = bf2f(VT_lds[d * 264 + q]);
        const int pix = vert ? iw * 256 + q : (q >> 2) * 64 + iw * 4 + (q & 3);
        attT[((size_t)b * NPIX + pix) * 512 + ch + d] = f2bf(o[qt][dt][jj] * li[jj] + lep);
      }
    }
  }
}

// ---------------------------------------------------------------------------
extern "C" void kernel_launch(void* const* d_in, const int* in_sizes, int n_in,
                              void* d_out, int out_size, void* d_ws, size_t ws_size,
                              hipStream_t stream) {
  const float* fmap     = (const float*)d_in[0];
  const float* w_qk     = (const float*)d_in[1];
  const float* w_v      = (const float*)d_in[2];
  const float* w_v_vert = (const float*)d_in[3];
  const float* w_proj   = (const float*)d_in[5];
  float* out = (float*)d_out;

  ushort_t* XT   = (ushort_t*)d_ws;                       // [8][4096][512]
  ushort_t* qkvb = XT + (size_t)8 * NPIX * 512;           // [8][1792][4096]
  ushort_t* attT = qkvb + (size_t)8 * 1792 * NPIX;        // [8][4096][512]
  ushort_t* WA   = attT + (size_t)8 * NPIX * 512;         // [1792][512]
  ushort_t* WPb  = WA + (size_t)1792 * 512;               // [512][512]

  dim3 blk(256);
  cast_bf16<<<512, blk, 0, stream>>>(w_qk, WA, 1024 * 512);
  cast_bf16<<<256, blk, 0, stream>>>(w_v, WA + (size_t)1024 * 512, 512 * 512);
  cast_bf16<<<256, blk, 0, stream>>>(w_proj, WPb, 512 * 512);
  lepe_w<<<256, blk, 0, stream>>>(w_v_vert, w_v, WA + (size_t)1536 * 512);
  transpose_cast<<<dim3(64, 8, 8), blk, 0, stream>>>(fmap, XT);
  gemm_mfma<<<dim3(32, 14, 8), blk, 0, stream>>>(
      WA, XT, qkvb, nullptr, (long)NPIX * 512, (long)1792 * NPIX, 0);
  attn_mfma<<<dim3(8, 128, 2), blk, 0, stream>>>(qkvb, attT);
  gemm_mfma<<<dim3(32, 4, 8), blk, 0, stream>>>(
      WPb, attT, out, fmap, (long)NPIX * 512, (long)512 * NPIX, 1);
}